// Round 1
// baseline (505.197 us; speedup 1.0000x reference)
//
#include <hip/hip_runtime.h>
#include <hip/hip_bf16.h>

// Problem dims
#define B_   8
#define KS_  64     // query slots
#define L_   4096   // keys
#define D_   1024
#define H_   16
#define HD_  64
#define SCALE_ 0.125f   // HD^-0.5

typedef __attribute__((ext_vector_type(8))) short short8;            // 8 x bf16 MFMA operand
typedef __attribute__((ext_vector_type(8))) unsigned short ushort8;  // 16B load
typedef __attribute__((ext_vector_type(4))) unsigned short ushort4v; // 8B store
typedef __attribute__((ext_vector_type(4))) float f32x4;

__device__ __forceinline__ unsigned short f2b(float f) {
  // fp32 -> bf16, round-to-nearest-even (finite values only here)
  union { float f; unsigned u; } v; v.f = f;
  unsigned r = v.u + 0x7fffu + ((v.u >> 16) & 1u);
  return (unsigned short)(r >> 16);
}

// ---------------------------------------------------------------------------
// Weight convert: 4 x [1024x1024] fp32 -> bf16, contiguous in ws
// ---------------------------------------------------------------------------
__global__ __launch_bounds__(256) void wcvt(const float* __restrict__ wq,
                                            const float* __restrict__ wk,
                                            const float* __restrict__ wv,
                                            const float* __restrict__ wo,
                                            unsigned short* __restrict__ out) {
  int i = blockIdx.x * 256 + threadIdx.x;      // float4 index; 4 * 2^18 total
  int seg = i >> 18;
  int off = (i & 0x3ffff) << 2;
  const float* src = (seg == 0) ? wq : (seg == 1) ? wk : (seg == 2) ? wv : wo;
  f32x4 v = *(const f32x4*)(src + off);
  ushort4v o;
#pragma unroll
  for (int j = 0; j < 4; ++j) o[j] = f2b(v[j]);
  *(ushort4v*)(out + ((size_t)seg << 20) + off) = o;
}

// ---------------------------------------------------------------------------
// GEMM: C[M][1024] = A[M][1024] @ W[1024][1024]^T   (torch-Linear layout)
//   A: fp32 (A_F32) or bf16; W: bf16 row-major [N][K]; C: bf16, or fp32+bias.
//   128x128 tile, BK=32, 4 waves (2x2), 16x16x32 bf16 MFMA, 4x4 frags/wave.
//   M must be a multiple of 128 (true for 512 and 32768).
// ---------------------------------------------------------------------------
template <bool A_F32, bool OUT_F32B>
__global__ __launch_bounds__(256) void gemm128(const void* __restrict__ Ap,
                                               const unsigned short* __restrict__ W,
                                               void* __restrict__ Cp,
                                               const float* __restrict__ bias) {
  __shared__ unsigned short a_lds[128][40];   // 80B rows: 16B-aligned, 2-way banks (free)
  __shared__ unsigned short b_lds[128][40];
  const int tid  = threadIdx.x;
  const int lane = tid & 63;
  const int wv   = tid >> 6;
  const int g    = lane >> 4, c15 = lane & 15;
  const int wm   = wv >> 1,  wn  = wv & 1;
  const long m0  = (long)blockIdx.x * 128;
  const int  n0  = blockIdx.y * 128;

  const float*          Af = (const float*)Ap;
  const unsigned short* Ab = (const unsigned short*)Ap;

  f32x4 acc[4][4] = {};
  f32x4   areg[4];
  ushort8 abreg[2];
  ushort8 breg[2];

  auto load_tile = [&](int kt) {
    if constexpr (A_F32) {
#pragma unroll
      for (int q = 0; q < 4; ++q) {
        int flat = q * 256 + tid;
        int row = flat >> 3, c4 = flat & 7;            // 8 float4 per 32-col row
        areg[q] = *(const f32x4*)(Af + (m0 + row) * 1024 + kt * 32 + c4 * 4);
      }
    } else {
#pragma unroll
      for (int q = 0; q < 2; ++q) {
        int flat = q * 256 + tid;
        int row = flat >> 2, c8 = flat & 3;            // 4 x 8-elem chunks per row
        abreg[q] = *(const ushort8*)(Ab + (m0 + row) * 1024 + kt * 32 + c8 * 8);
      }
    }
#pragma unroll
    for (int q = 0; q < 2; ++q) {
      int flat = q * 256 + tid;
      int row = flat >> 2, c8 = flat & 3;
      breg[q] = *(const ushort8*)(W + (long)(n0 + row) * 1024 + kt * 32 + c8 * 8);
    }
  };

  load_tile(0);

  for (int kt = 0; kt < 32; ++kt) {
    __syncthreads();                       // previous iter's LDS readers done
    if constexpr (A_F32) {
#pragma unroll
      for (int q = 0; q < 4; ++q) {
        int flat = q * 256 + tid;
        int row = flat >> 3, c4 = flat & 7;
        ushort4v t;
#pragma unroll
        for (int j = 0; j < 4; ++j) t[j] = f2b(areg[q][j]);
        *(ushort4v*)&a_lds[row][c4 * 4] = t;
      }
    } else {
#pragma unroll
      for (int q = 0; q < 2; ++q) {
        int flat = q * 256 + tid;
        int row = flat >> 2, c8 = flat & 3;
        *(ushort8*)&a_lds[row][c8 * 8] = abreg[q];
      }
    }
#pragma unroll
    for (int q = 0; q < 2; ++q) {
      int flat = q * 256 + tid;
      int row = flat >> 2, c8 = flat & 3;
      *(ushort8*)&b_lds[row][c8 * 8] = breg[q];
    }
    if (kt + 1 < 32) load_tile(kt + 1);    // issue next-tile loads; overlap compute
    __syncthreads();                       // staging visible

    short8 af[4];
#pragma unroll
    for (int m = 0; m < 4; ++m)
      af[m] = *(const short8*)&a_lds[wm * 64 + m * 16 + c15][g * 8];
#pragma unroll
    for (int n = 0; n < 4; ++n) {
      short8 bf = *(const short8*)&b_lds[wn * 64 + n * 16 + c15][g * 8];
#pragma unroll
      for (int m = 0; m < 4; ++m)
        acc[m][n] = __builtin_amdgcn_mfma_f32_16x16x32_bf16(af[m], bf, acc[m][n], 0, 0, 0);
    }
  }

  // Epilogue: C/D layout col = lane&15, row = (lane>>4)*4 + reg
#pragma unroll
  for (int m = 0; m < 4; ++m) {
#pragma unroll
    for (int n = 0; n < 4; ++n) {
#pragma unroll
      for (int r = 0; r < 4; ++r) {
        long row = m0 + wm * 64 + m * 16 + g * 4 + r;
        int  col = n0 + wn * 64 + n * 16 + c15;
        if constexpr (OUT_F32B) {
          ((float*)Cp)[row * 1024 + col] = acc[m][n][r] + bias[col];
        } else {
          ((unsigned short*)Cp)[row * 1024 + col] = f2b(acc[m][n][r]);
        }
      }
    }
  }
}

// ---------------------------------------------------------------------------
// Attention pass 1: per (b,h): rowsum[slot] = sum_l softmax_slot(S[:,l])[slot]
//   S = Q_h @ K_h^T * SCALE.  1 block per (b,h), 8 waves, L tiled by 128.
//   Wave w owns l-columns w*16..w*16+15 of each tile (n-frag = lane&15).
//   C-layout: col (=l) = lane&15 -> whole softmax column is in one lane-quad:
//   in-lane over 16 regs + shfl_xor(16) + shfl_xor(32).
// ---------------------------------------------------------------------------
__global__ __launch_bounds__(512) void attn_pass1(const unsigned short* __restrict__ q_b,
                                                  const unsigned short* __restrict__ k_b,
                                                  float* __restrict__ rs_g) {
  __shared__ unsigned short q_lds[64][72];    // 144B rows: 16B aligned, 2-way banks
  __shared__ unsigned short k_lds[128][72];
  __shared__ float rs_lds[8][64];
  const int bh = blockIdx.x;
  const int b = bh >> 4, h = bh & 15;
  const int tid = threadIdx.x;
  const int w = tid >> 6, lane = tid & 63;
  const int g = lane >> 4, c15 = lane & 15;

  {  // stage Q_h [64][64]
    int slot = tid >> 3, cc = (tid & 7) * 8;
    *(ushort8*)&q_lds[slot][cc] =
        *(const ushort8*)(q_b + (long)(b * 64 + slot) * 1024 + h * 64 + cc);
  }

  float rs[4][4] = {};
  const long kbase = (long)b * L_ * D_ + h * 64;
  const int  sl = tid >> 2, sc = (tid & 3) * 16;

  for (int it = 0; it < 32; ++it) {
    const int l0 = it * 128;
    ushort8 k0 = *(const ushort8*)(k_b + kbase + (long)(l0 + sl) * 1024 + sc);
    ushort8 k1 = *(const ushort8*)(k_b + kbase + (long)(l0 + sl) * 1024 + sc + 8);
    __syncthreads();
    *(ushort8*)&k_lds[sl][sc]     = k0;
    *(ushort8*)&k_lds[sl][sc + 8] = k1;
    __syncthreads();

    f32x4 s[4] = {};
#pragma unroll
    for (int ks = 0; ks < 2; ++ks) {
      short8 bf = *(const short8*)&k_lds[w * 16 + c15][ks * 32 + g * 8];
#pragma unroll
      for (int m = 0; m < 4; ++m) {
        short8 af = *(const short8*)&q_lds[m * 16 + c15][ks * 32 + g * 8];
        s[m] = __builtin_amdgcn_mfma_f32_16x16x32_bf16(af, bf, s[m], 0, 0, 0);
      }
    }
    float mx = -1e30f;
#pragma unroll
    for (int m = 0; m < 4; ++m)
#pragma unroll
      for (int r = 0; r < 4; ++r) mx = fmaxf(mx, s[m][r]);
    mx = fmaxf(mx, __shfl_xor(mx, 16));
    mx = fmaxf(mx, __shfl_xor(mx, 32));
    float p[4][4];
    float sum = 0.f;
#pragma unroll
    for (int m = 0; m < 4; ++m)
#pragma unroll
      for (int r = 0; r < 4; ++r) {
        p[m][r] = __expf((s[m][r] - mx) * SCALE_);
        sum += p[m][r];
      }
    sum += __shfl_xor(sum, 16);
    sum += __shfl_xor(sum, 32);
    float rinv = 1.0f / sum;
#pragma unroll
    for (int m = 0; m < 4; ++m)
#pragma unroll
      for (int r = 0; r < 4; ++r) rs[m][r] += p[m][r] * rinv;  // lane-local partial
  }
  // reduce over the 16-lane column group, then across waves via LDS
#pragma unroll
  for (int m = 0; m < 4; ++m)
#pragma unroll
    for (int r = 0; r < 4; ++r) {
      float v = rs[m][r];
      v += __shfl_xor(v, 1); v += __shfl_xor(v, 2);
      v += __shfl_xor(v, 4); v += __shfl_xor(v, 8);
      if (c15 == 0) rs_lds[w][m * 16 + g * 4 + r] = v;
    }
  __syncthreads();
  if (tid < 64) {
    float t = 0.f;
#pragma unroll
    for (int w2 = 0; w2 < 8; ++w2) t += rs_lds[w2][tid];
    rs_g[bh * 64 + tid] = t;
  }
}

// ---------------------------------------------------------------------------
// Attention pass 2: recompute softmax (bit-identical), scale by 1/(rs+1e-8),
// write attn (fp32, coalesced), and PV via LDS round-trip:
//   pt[slot][l] (P scaled, bf16) as MFMA-A; vt[c][l] (V^T) as MFMA-B.
// Each wave owns 2 of the 16 output frags -> no cross-wave out reduce.
// ---------------------------------------------------------------------------
__global__ __launch_bounds__(512) void attn_pass2(const unsigned short* __restrict__ q_b,
                                                  const unsigned short* __restrict__ k_b,
                                                  const unsigned short* __restrict__ v_b,
                                                  const float* __restrict__ rs_g,
                                                  float* __restrict__ attn,
                                                  unsigned short* __restrict__ oh) {
  __shared__ unsigned short q_lds[64][72];
  __shared__ unsigned short k_lds[128][72];
  __shared__ unsigned short vt_lds[64][136];  // 272B rows: 16B aligned
  __shared__ unsigned short pt_lds[64][136];
  const int bh = blockIdx.x;
  const int b = bh >> 4, h = bh & 15;
  const int tid = threadIdx.x;
  const int w = tid >> 6, lane = tid & 63;
  const int g = lane >> 4, c15 = lane & 15;

  {
    int slot = tid >> 3, cc = (tid & 7) * 8;
    *(ushort8*)&q_lds[slot][cc] =
        *(const ushort8*)(q_b + (long)(b * 64 + slot) * 1024 + h * 64 + cc);
  }

  float inv_r[4][4];
#pragma unroll
  for (int m = 0; m < 4; ++m)
#pragma unroll
    for (int r = 0; r < 4; ++r)
      inv_r[m][r] = 1.0f / (rs_g[bh * 64 + m * 16 + g * 4 + r] + 1e-8f);

  f32x4 oacc[2] = {};
  const int m_pv = w >> 1, n_pv0 = (w & 1) * 2;
  float* attn_base = attn + (long)bh * KS_ * L_;
  const long base_bld = (long)b * L_ * D_ + h * 64;
  const int  sl = tid >> 2, sc = (tid & 3) * 16;

  for (int it = 0; it < 32; ++it) {
    const int l0 = it * 128;
    ushort8 k0 = *(const ushort8*)(k_b + base_bld + (long)(l0 + sl) * 1024 + sc);
    ushort8 k1 = *(const ushort8*)(k_b + base_bld + (long)(l0 + sl) * 1024 + sc + 8);
    ushort8 v0 = *(const ushort8*)(v_b + base_bld + (long)(l0 + sl) * 1024 + sc);
    ushort8 v1 = *(const ushort8*)(v_b + base_bld + (long)(l0 + sl) * 1024 + sc + 8);
    __syncthreads();                         // prev QK^T + PV reads done
    *(ushort8*)&k_lds[sl][sc]     = k0;
    *(ushort8*)&k_lds[sl][sc + 8] = k1;
#pragma unroll
    for (int j = 0; j < 8; ++j) {            // V^T scatter (u16; ~few-way conflicts, ok r1)
      vt_lds[sc + j][sl]     = v0[j];
      vt_lds[sc + 8 + j][sl] = v1[j];
    }
    __syncthreads();                         // staging visible

    f32x4 s[4] = {};
#pragma unroll
    for (int ks = 0; ks < 2; ++ks) {
      short8 bf = *(const short8*)&k_lds[w * 16 + c15][ks * 32 + g * 8];
#pragma unroll
      for (int m = 0; m < 4; ++m) {
        short8 af = *(const short8*)&q_lds[m * 16 + c15][ks * 32 + g * 8];
        s[m] = __builtin_amdgcn_mfma_f32_16x16x32_bf16(af, bf, s[m], 0, 0, 0);
      }
    }
    float mx = -1e30f;
#pragma unroll
    for (int m = 0; m < 4; ++m)
#pragma unroll
      for (int r = 0; r < 4; ++r) mx = fmaxf(mx, s[m][r]);
    mx = fmaxf(mx, __shfl_xor(mx, 16));
    mx = fmaxf(mx, __shfl_xor(mx, 32));
    float p[4][4];
    float sum = 0.f;
#pragma unroll
    for (int m = 0; m < 4; ++m)
#pragma unroll
      for (int r = 0; r < 4; ++r) {
        p[m][r] = __expf((s[m][r] - mx) * SCALE_);
        sum += p[m][r];
      }
    sum += __shfl_xor(sum, 16);
    sum += __shfl_xor(sum, 32);
    float rinv = 1.0f / sum;

    const int lloc = w * 16 + c15;
#pragma unroll
    for (int m = 0; m < 4; ++m)
#pragma unroll
      for (int r = 0; r < 4; ++r) {
        float ps = p[m][r] * rinv * inv_r[m][r];
        attn_base[(long)(m * 16 + g * 4 + r) * L_ + l0 + lloc] = ps;   // final attn
        pt_lds[m * 16 + g * 4 + r][lloc] = f2b(ps);
      }
    __syncthreads();                         // pt visible

#pragma unroll
    for (int ks = 0; ks < 4; ++ks) {
      short8 pa = *(const short8*)&pt_lds[m_pv * 16 + c15][ks * 32 + g * 8];
#pragma unroll
      for (int n2 = 0; n2 < 2; ++n2) {
        short8 vb = *(const short8*)&vt_lds[(n_pv0 + n2) * 16 + c15][ks * 32 + g * 8];
        oacc[n2] = __builtin_amdgcn_mfma_f32_16x16x32_bf16(pa, vb, oacc[n2], 0, 0, 0);
      }
    }
  }

  // out_heads [B,K,D] bf16, d = h*64 + c  (already rowsum-scaled via ps)
#pragma unroll
  for (int n2 = 0; n2 < 2; ++n2)
#pragma unroll
    for (int r = 0; r < 4; ++r) {
      int slot = m_pv * 16 + g * 4 + r;
      int c    = (n_pv0 + n2) * 16 + c15;
      oh[(long)(b * 64 + slot) * 1024 + h * 64 + c] = f2b(oacc[n2][r]);
    }
}

// ---------------------------------------------------------------------------
extern "C" void kernel_launch(void* const* d_in, const int* in_sizes, int n_in,
                              void* d_out, int out_size, void* d_ws, size_t ws_size,
                              hipStream_t stream) {
  (void)in_sizes; (void)n_in; (void)out_size; (void)ws_size;
  const float* query = (const float*)d_in[0];
  const float* key   = (const float*)d_in[1];
  const float* value = (const float*)d_in[2];
  const float* Wq    = (const float*)d_in[3];
  const float* Wk    = (const float*)d_in[4];
  const float* Wv    = (const float*)d_in[5];
  const float* Wo    = (const float*)d_in[6];
  const float* bo    = (const float*)d_in[7];

  char* ws = (char*)d_ws;
  // ws layout (bytes): needs ~139 MB
  unsigned short* w_all = (unsigned short*)(ws);                    // 4 x 1M bf16 = 8 MB
  unsigned short* wq_b  = w_all;
  unsigned short* wk_b  = w_all + (1u << 20);
  unsigned short* wv_b  = w_all + (2u << 20);
  unsigned short* wo_b  = w_all + (3u << 20);
  unsigned short* q_b   = (unsigned short*)(ws + ((size_t)8  << 20));  // 1 MB
  unsigned short* oh    = (unsigned short*)(ws + ((size_t)9  << 20));  // 1 MB
  float*          rs_g  = (float*)         (ws + ((size_t)10 << 20));  // 32 KB
  unsigned short* k_b   = (unsigned short*)(ws + ((size_t)11 << 20));  // 64 MB
  unsigned short* v_b   = (unsigned short*)(ws + ((size_t)75 << 20));  // 64 MB

  float* out  = (float*)d_out;                       // [B,K,D] = 524288
  float* attn = out + (size_t)B_ * KS_ * D_;         // [B,H,K,L] = 33554432

  wcvt<<<4096, 256, 0, stream>>>(Wq, Wk, Wv, Wo, w_all);

  gemm128<true, false><<<dim3(4, 8),   256, 0, stream>>>(query, wq_b, q_b, nullptr);
  gemm128<true, false><<<dim3(256, 8), 256, 0, stream>>>(key,   wk_b, k_b, nullptr);
  gemm128<true, false><<<dim3(256, 8), 256, 0, stream>>>(value, wv_b, v_b, nullptr);

  attn_pass1<<<B_ * H_, 512, 0, stream>>>(q_b, k_b, rs_g);
  attn_pass2<<<B_ * H_, 512, 0, stream>>>(q_b, k_b, v_b, rs_g, attn, oh);

  gemm128<false, true><<<dim3(4, 8), 256, 0, stream>>>(oh, wo_b, out, bo);
}

// Round 2
// 479.030 us; speedup vs baseline: 1.0546x; 1.0546x over previous
//
#include <hip/hip_runtime.h>
#include <hip/hip_bf16.h>

#define B_   8
#define KS_  64
#define L_   4096
#define D_   1024
#define H_   16
#define HD_  64
#define SCALE_ 0.125f

typedef __attribute__((ext_vector_type(8))) short short8;
typedef __attribute__((ext_vector_type(8))) unsigned short ushort8;
typedef __attribute__((ext_vector_type(4))) unsigned short ushort4v;
typedef __attribute__((ext_vector_type(4))) float f32x4;

__device__ __forceinline__ unsigned short f2b(float f) {
  union { float f; unsigned u; } v; v.f = f;
  unsigned r = v.u + 0x7fffu + ((v.u >> 16) & 1u);
  return (unsigned short)(r >> 16);
}

typedef const __attribute__((address_space(1))) void gas_void;
typedef __attribute__((address_space(3))) void las_void;
__device__ __forceinline__ void gl2lds16(const void* g, void* l) {
  __builtin_amdgcn_global_load_lds((gas_void*)g, (las_void*)l, 16, 0, 0);
}

// ---------------------------------------------------------------------------
// Weight convert: 4 x [1024x1024] fp32 -> bf16 contiguous in ws
// ---------------------------------------------------------------------------
__global__ __launch_bounds__(256) void wcvt(const float* __restrict__ wq,
                                            const float* __restrict__ wk,
                                            const float* __restrict__ wv,
                                            const float* __restrict__ wo,
                                            unsigned short* __restrict__ out) {
  int i = blockIdx.x * 256 + threadIdx.x;
  int seg = i >> 18;
  int off = (i & 0x3ffff) << 2;
  const float* src = (seg == 0) ? wq : (seg == 1) ? wk : (seg == 2) ? wv : wo;
  f32x4 v = *(const f32x4*)(src + off);
  ushort4v o;
#pragma unroll
  for (int j = 0; j < 4; ++j) o[j] = f2b(v[j]);
  *(ushort4v*)(out + ((size_t)seg << 20) + off) = o;
}

// ---------------------------------------------------------------------------
// GEMM: C[M][1024] = A[M][1024](fp32) @ W[1024][1024]^T(bf16)
//  m97-structure: 128x128 tile, BK=32, 4 waves (2x2), global_load_lds(16B),
//  double-buffered LDS, 1 barrier/K-step, n-fast grid + bijective XCD swizzle.
//  A staged as fp32 (col-XOR-swizzled via pre-swizzled global source, rule#21),
//  converted to bf16 at frag read. grid.x = nm*8, nm = M/128.
// ---------------------------------------------------------------------------
template <bool OUT_F32B>
__global__ __launch_bounds__(256) void gemm_a32(const float* __restrict__ A,
                                                const unsigned short* __restrict__ W,
                                                void* __restrict__ Cp,
                                                const float* __restrict__ bias) {
  __shared__ __align__(16) char smem[49152];           // 48 KB -> 3 blocks/CU
  float*          a_lds0 = (float*)smem;               // [128][32] f32 = 16 KB
  float*          a_lds1 = (float*)(smem + 16384);
  unsigned short* b_lds0 = (unsigned short*)(smem + 32768);  // [128][32] bf16 = 8 KB
  unsigned short* b_lds1 = (unsigned short*)(smem + 40960);

  const int tid = threadIdx.x, lane = tid & 63, wv = tid >> 6;
  const int g = lane >> 4, c15 = lane & 15;
  const int wm = wv >> 1, wn = wv & 1;

  // bijective XCD swizzle (gridDim.x % 8 == 0 in all launches), n-fast decode
  const int nwg = gridDim.x;
  const int swz = (blockIdx.x & 7) * (nwg >> 3) + (blockIdx.x >> 3);
  const long m0 = (long)(swz >> 3) * 128;
  const int  n0 = (swz & 7) * 128;

  // staging source addressing
  const int l8 = lane & 7, lhi = lane >> 3;            // A: 8 lanes/row
  const int acol = (l8 ^ lhi) << 2;                    // XOR-swizzled f32 col
  const int bl4 = lane & 3, blr = lane >> 2;           // B: 4 lanes/row
  const float*          a_src = A + m0 * 1024 + acol;
  const unsigned short* b_src = W + (long)n0 * 1024 + bl4 * 8;

  f32x4 acc[4][4] = {};

  auto stage = [&](float* ab, unsigned short* bb, int kt) {
#pragma unroll
    for (int q = 0; q < 4; ++q) {
      int row = (wv * 4 + q) * 8 + lhi;
      gl2lds16(a_src + (long)row * 1024 + kt * 32, ab + (wv * 4 + q) * 256);
    }
#pragma unroll
    for (int q = 0; q < 2; ++q) {
      int row = (wv * 2 + q) * 16 + blr;
      gl2lds16(b_src + (long)row * 1024 + kt * 32, bb + (wv * 2 + q) * 512);
    }
  };

  stage(a_lds0, b_lds0, 0);
  __syncthreads();                                     // drains vmcnt(0)

  int cur = 0;
  for (int kt = 0; kt < 32; ++kt) {
    float*          ab = cur ? a_lds1 : a_lds0;
    unsigned short* bb = cur ? b_lds1 : b_lds0;
    if (kt + 1 < 32) stage(cur ? a_lds0 : a_lds1, cur ? b_lds0 : b_lds1, kt + 1);

    short8 af[4];
#pragma unroll
    for (int m = 0; m < 4; ++m) {
      int r = wm * 64 + m * 16 + c15;
      int s0 = ((g * 2)     ^ (c15 & 7)) * 4;          // swizzled 4-f32 slots
      int s1 = ((g * 2 + 1) ^ (c15 & 7)) * 4;
      f32x4 lo = *(const f32x4*)&ab[r * 32 + s0];
      f32x4 hi = *(const f32x4*)&ab[r * 32 + s1];
      short8 t;
#pragma unroll
      for (int i = 0; i < 4; ++i) { t[i] = (short)f2b(lo[i]); t[i + 4] = (short)f2b(hi[i]); }
      af[m] = t;
    }
#pragma unroll
    for (int n = 0; n < 4; ++n) {
      int r = wn * 64 + n * 16 + c15;
      short8 bf = *(const short8*)&bb[r * 32 + g * 8];
#pragma unroll
      for (int m = 0; m < 4; ++m)
        acc[m][n] = __builtin_amdgcn_mfma_f32_16x16x32_bf16(af[m], bf, acc[m][n], 0, 0, 0);
    }
    __syncthreads();                                   // next buf staged; cur reads done
    cur ^= 1;
  }

  if constexpr (OUT_F32B) {
    float* Cf = (float*)Cp;
#pragma unroll
    for (int m = 0; m < 4; ++m)
#pragma unroll
      for (int n = 0; n < 4; ++n)
#pragma unroll
        for (int r = 0; r < 4; ++r) {
          long row = m0 + wm * 64 + m * 16 + g * 4 + r;
          int  col = n0 + wn * 64 + n * 16 + c15;
          Cf[row * 1024 + col] = acc[m][n][r] + bias[col];
        }
  } else {
    // stage C tile in LDS (reuse smem), then 128B-contiguous stores
    unsigned short* c_lds = (unsigned short*)smem;     // [128][132] = 33.8 KB
#pragma unroll
    for (int m = 0; m < 4; ++m)
#pragma unroll
      for (int n = 0; n < 4; ++n)
#pragma unroll
        for (int r = 0; r < 4; ++r)
          c_lds[(wm * 64 + m * 16 + g * 4 + r) * 132 + wn * 64 + n * 16 + c15] =
              f2b(acc[m][n][r]);
    __syncthreads();
    unsigned short* Cb = (unsigned short*)Cp;
    const int row = tid >> 1, half = tid & 1;
    unsigned short*       dst = Cb + (m0 + row) * 1024 + n0 + half * 64;
    const unsigned short* sl  = &c_lds[row * 132 + half * 64];
#pragma unroll
    for (int i = 0; i < 8; ++i)
      *(ushort8*)(dst + i * 8) = *(const ushort8*)(sl + i * 8);
  }
}

// ---------------------------------------------------------------------------
// Attention pass 1 (L-split x4): partial rowsums over 1024 keys per block.
// grid 512 = (bh*4 + chunk), 8 waves. Softmax over slots is in-lane (col=l).
// ---------------------------------------------------------------------------
__global__ __launch_bounds__(512) void attn_pass1(const unsigned short* __restrict__ q_b,
                                                  const unsigned short* __restrict__ k_b,
                                                  float* __restrict__ rs_part) {
  __shared__ unsigned short q_lds[64][72];
  __shared__ unsigned short k_lds[128][72];
  __shared__ float rs_lds[8][64];
  const int bh = blockIdx.x >> 2, ch = blockIdx.x & 3;
  const int b = bh >> 4, h = bh & 15;
  const int tid = threadIdx.x;
  const int w = tid >> 6, lane = tid & 63;
  const int g = lane >> 4, c15 = lane & 15;

  {
    int slot = tid >> 3, cc = (tid & 7) * 8;
    *(ushort8*)&q_lds[slot][cc] =
        *(const ushort8*)(q_b + (long)(b * 64 + slot) * 1024 + h * 64 + cc);
  }

  float rs[4][4] = {};
  const long kbase = (long)b * L_ * D_ + h * 64;
  const int  sl = tid >> 2, sc = (tid & 3) * 16;

  for (int it = ch * 8; it < ch * 8 + 8; ++it) {
    const int l0 = it * 128;
    ushort8 k0 = *(const ushort8*)(k_b + kbase + (long)(l0 + sl) * 1024 + sc);
    ushort8 k1 = *(const ushort8*)(k_b + kbase + (long)(l0 + sl) * 1024 + sc + 8);
    __syncthreads();
    *(ushort8*)&k_lds[sl][sc]     = k0;
    *(ushort8*)&k_lds[sl][sc + 8] = k1;
    __syncthreads();

    f32x4 s[4] = {};
#pragma unroll
    for (int ks = 0; ks < 2; ++ks) {
      short8 bf = *(const short8*)&k_lds[w * 16 + c15][ks * 32 + g * 8];
#pragma unroll
      for (int m = 0; m < 4; ++m) {
        short8 af = *(const short8*)&q_lds[m * 16 + c15][ks * 32 + g * 8];
        s[m] = __builtin_amdgcn_mfma_f32_16x16x32_bf16(af, bf, s[m], 0, 0, 0);
      }
    }
    float mx = -1e30f;
#pragma unroll
    for (int m = 0; m < 4; ++m)
#pragma unroll
      for (int r = 0; r < 4; ++r) mx = fmaxf(mx, s[m][r]);
    mx = fmaxf(mx, __shfl_xor(mx, 16));
    mx = fmaxf(mx, __shfl_xor(mx, 32));
    float sum = 0.f, p[4][4];
#pragma unroll
    for (int m = 0; m < 4; ++m)
#pragma unroll
      for (int r = 0; r < 4; ++r) { p[m][r] = __expf((s[m][r] - mx) * SCALE_); sum += p[m][r]; }
    sum += __shfl_xor(sum, 16);
    sum += __shfl_xor(sum, 32);
    float rinv = 1.0f / sum;
#pragma unroll
    for (int m = 0; m < 4; ++m)
#pragma unroll
      for (int r = 0; r < 4; ++r) rs[m][r] += p[m][r] * rinv;
  }
#pragma unroll
  for (int m = 0; m < 4; ++m)
#pragma unroll
    for (int r = 0; r < 4; ++r) {
      float v = rs[m][r];
      v += __shfl_xor(v, 1); v += __shfl_xor(v, 2);
      v += __shfl_xor(v, 4); v += __shfl_xor(v, 8);
      if (c15 == 0) rs_lds[w][m * 16 + g * 4 + r] = v;
    }
  __syncthreads();
  if (tid < 64) {
    float t = 0.f;
#pragma unroll
    for (int w2 = 0; w2 < 8; ++w2) t += rs_lds[w2][tid];
    rs_part[(bh * 4 + ch) * 64 + tid] = t;
  }
}

// ---------------------------------------------------------------------------
// Attention pass 2 (L-split x4): recompute softmax, scale by 1/(rowsum+1e-8),
// write attn fp32, PV partial -> op_part[bh][ch][64][64] fp32.
// ---------------------------------------------------------------------------
__global__ __launch_bounds__(512) void attn_pass2(const unsigned short* __restrict__ q_b,
                                                  const unsigned short* __restrict__ k_b,
                                                  const unsigned short* __restrict__ v_b,
                                                  const float* __restrict__ rs_part,
                                                  float* __restrict__ attn,
                                                  float* __restrict__ op_part) {
  __shared__ unsigned short q_lds[64][72];
  __shared__ unsigned short k_lds[128][72];
  __shared__ unsigned short vt_lds[64][136];
  __shared__ unsigned short pt_lds[64][136];
  const int bh = blockIdx.x >> 2, ch = blockIdx.x & 3;
  const int b = bh >> 4, h = bh & 15;
  const int tid = threadIdx.x;
  const int w = tid >> 6, lane = tid & 63;
  const int g = lane >> 4, c15 = lane & 15;

  {
    int slot = tid >> 3, cc = (tid & 7) * 8;
    *(ushort8*)&q_lds[slot][cc] =
        *(const ushort8*)(q_b + (long)(b * 64 + slot) * 1024 + h * 64 + cc);
  }

  float inv_r[4][4];
#pragma unroll
  for (int m = 0; m < 4; ++m)
#pragma unroll
    for (int r = 0; r < 4; ++r) {
      int slot = m * 16 + g * 4 + r;
      float s = 0.f;
#pragma unroll
      for (int c = 0; c < 4; ++c) s += rs_part[(bh * 4 + c) * 64 + slot];
      inv_r[m][r] = 1.0f / (s + 1e-8f);
    }

  f32x4 oacc[2] = {};
  const int m_pv = w >> 1, n_pv0 = (w & 1) * 2;
  float* attn_base = attn + (long)bh * KS_ * L_;
  const long base_bld = (long)b * L_ * D_ + h * 64;
  const int  sl = tid >> 2, sc = (tid & 3) * 16;

  for (int it = ch * 8; it < ch * 8 + 8; ++it) {
    const int l0 = it * 128;
    ushort8 k0 = *(const ushort8*)(k_b + base_bld + (long)(l0 + sl) * 1024 + sc);
    ushort8 k1 = *(const ushort8*)(k_b + base_bld + (long)(l0 + sl) * 1024 + sc + 8);
    ushort8 v0 = *(const ushort8*)(v_b + base_bld + (long)(l0 + sl) * 1024 + sc);
    ushort8 v1 = *(const ushort8*)(v_b + base_bld + (long)(l0 + sl) * 1024 + sc + 8);
    __syncthreads();
    *(ushort8*)&k_lds[sl][sc]     = k0;
    *(ushort8*)&k_lds[sl][sc + 8] = k1;
#pragma unroll
    for (int j = 0; j < 8; ++j) {
      vt_lds[sc + j][sl]     = v0[j];
      vt_lds[sc + 8 + j][sl] = v1[j];
    }
    __syncthreads();

    f32x4 s[4] = {};
#pragma unroll
    for (int ks = 0; ks < 2; ++ks) {
      short8 bf = *(const short8*)&k_lds[w * 16 + c15][ks * 32 + g * 8];
#pragma unroll
      for (int m = 0; m < 4; ++m) {
        short8 af = *(const short8*)&q_lds[m * 16 + c15][ks * 32 + g * 8];
        s[m] = __builtin_amdgcn_mfma_f32_16x16x32_bf16(af, bf, s[m], 0, 0, 0);
      }
    }
    float mx = -1e30f;
#pragma unroll
    for (int m = 0; m < 4; ++m)
#pragma unroll
      for (int r = 0; r < 4; ++r) mx = fmaxf(mx, s[m][r]);
    mx = fmaxf(mx, __shfl_xor(mx, 16));
    mx = fmaxf(mx, __shfl_xor(mx, 32));
    float sum = 0.f, p[4][4];
#pragma unroll
    for (int m = 0; m < 4; ++m)
#pragma unroll
      for (int r = 0; r < 4; ++r) { p[m][r] = __expf((s[m][r] - mx) * SCALE_); sum += p[m][r]; }
    sum += __shfl_xor(sum, 16);
    sum += __shfl_xor(sum, 32);
    float rinv = 1.0f / sum;

    const int lloc = w * 16 + c15;
#pragma unroll
    for (int m = 0; m < 4; ++m)
#pragma unroll
      for (int r = 0; r < 4; ++r) {
        float ps = p[m][r] * rinv * inv_r[m][r];
        attn_base[(long)(m * 16 + g * 4 + r) * L_ + l0 + lloc] = ps;
        pt_lds[m * 16 + g * 4 + r][lloc] = f2b(ps);
      }
    __syncthreads();

#pragma unroll
    for (int ks = 0; ks < 4; ++ks) {
      short8 pa = *(const short8*)&pt_lds[m_pv * 16 + c15][ks * 32 + g * 8];
#pragma unroll
      for (int n2 = 0; n2 < 2; ++n2) {
        short8 vb = *(const short8*)&vt_lds[(n_pv0 + n2) * 16 + c15][ks * 32 + g * 8];
        oacc[n2] = __builtin_amdgcn_mfma_f32_16x16x32_bf16(pa, vb, oacc[n2], 0, 0, 0);
      }
    }
  }

#pragma unroll
  for (int n2 = 0; n2 < 2; ++n2)
#pragma unroll
    for (int r = 0; r < 4; ++r) {
      int slot = m_pv * 16 + g * 4 + r;
      int c    = (n_pv0 + n2) * 16 + c15;
      op_part[((long)(bh * 4 + ch) * 64 + slot) * 64 + c] = oacc[n2][r];
    }
}

// ---------------------------------------------------------------------------
// Reduce PV chunk-partials -> oh fp32 [512][1024]
// ---------------------------------------------------------------------------
__global__ __launch_bounds__(256) void oh_red(const float* __restrict__ op_part,
                                              float* __restrict__ oh) {
  int i = blockIdx.x * 256 + threadIdx.x;   // 524288 total
  int c = i & 63, slot = (i >> 6) & 63, bh = i >> 12;
  float s = 0.f;
#pragma unroll
  for (int ch = 0; ch < 4; ++ch)
    s += op_part[((long)(bh * 4 + ch) * 64 + slot) * 64 + c];
  int b = bh >> 4, h = bh & 15;
  oh[(long)(b * 64 + slot) * 1024 + h * 64 + c] = s;
}

// ---------------------------------------------------------------------------
extern "C" void kernel_launch(void* const* d_in, const int* in_sizes, int n_in,
                              void* d_out, int out_size, void* d_ws, size_t ws_size,
                              hipStream_t stream) {
  (void)in_sizes; (void)n_in; (void)out_size; (void)ws_size;
  const float* query = (const float*)d_in[0];
  const float* key   = (const float*)d_in[1];
  const float* value = (const float*)d_in[2];
  const float* Wq    = (const float*)d_in[3];
  const float* Wk    = (const float*)d_in[4];
  const float* Wv    = (const float*)d_in[5];
  const float* Wo    = (const float*)d_in[6];
  const float* bo    = (const float*)d_in[7];

  char* ws = (char*)d_ws;
  // ws layout (~148 MB total)
  unsigned short* w_all   = (unsigned short*)ws;                       // 8 MB
  unsigned short* wq_b    = w_all;
  unsigned short* wk_b    = w_all + (1u << 20);
  unsigned short* wv_b    = w_all + (2u << 20);
  unsigned short* wo_b    = w_all + (3u << 20);
  unsigned short* q_b     = (unsigned short*)(ws + ((size_t)8  << 20)); // 1 MB
  float*          oh_f32  = (float*)         (ws + ((size_t)9  << 20)); // 2 MB
  float*          rs_part = (float*)         (ws + ((size_t)11 << 20)); // 128 KB
  float*          op_part = (float*)         (ws + ((size_t)12 << 20)); // 8 MB
  unsigned short* k_b     = (unsigned short*)(ws + ((size_t)20 << 20)); // 64 MB
  unsigned short* v_b     = (unsigned short*)(ws + ((size_t)84 << 20)); // 64 MB

  float* out  = (float*)d_out;
  float* attn = out + (size_t)B_ * KS_ * D_;

  wcvt<<<4096, 256, 0, stream>>>(Wq, Wk, Wv, Wo, w_all);

  gemm_a32<false><<<32,   256, 0, stream>>>(query, wq_b, q_b, nullptr);
  gemm_a32<false><<<2048, 256, 0, stream>>>(key,   wk_b, k_b, nullptr);
  gemm_a32<false><<<2048, 256, 0, stream>>>(value, wv_b, v_b, nullptr);

  attn_pass1<<<512, 512, 0, stream>>>(q_b, k_b, rs_part);
  attn_pass2<<<512, 512, 0, stream>>>(q_b, k_b, v_b, rs_part, attn, op_part);
  oh_red<<<2048, 256, 0, stream>>>(op_part, oh_f32);

  gemm_a32<true><<<32, 256, 0, stream>>>(oh_f32, wo_b, out, bo);
}

// Round 3
// 420.916 us; speedup vs baseline: 1.2002x; 1.1381x over previous
//
#include <hip/hip_runtime.h>
#include <hip/hip_bf16.h>

#define B_   8
#define KS_  64
#define L_   4096
#define D_   1024
#define H_   16
#define HD_  64
#define SCALE_ 0.125f

typedef __attribute__((ext_vector_type(8))) short short8;
typedef __attribute__((ext_vector_type(8))) unsigned short ushort8;
typedef __attribute__((ext_vector_type(4))) unsigned short ushort4v;
typedef __attribute__((ext_vector_type(4))) float f32x4;

__device__ __forceinline__ unsigned short f2b(float f) {
  union { float f; unsigned u; } v; v.f = f;
  unsigned r = v.u + 0x7fffu + ((v.u >> 16) & 1u);
  return (unsigned short)(r >> 16);
}

typedef const __attribute__((address_space(1))) void gas_void;
typedef __attribute__((address_space(3))) void las_void;
__device__ __forceinline__ void gl2lds16(const void* g, void* l) {
  __builtin_amdgcn_global_load_lds((gas_void*)g, (las_void*)l, 16, 0, 0);
}

// ---------------------------------------------------------------------------
// Weight convert: 4 x [1024x1024] fp32 -> bf16 contiguous in ws
// ---------------------------------------------------------------------------
__global__ __launch_bounds__(256) void wcvt(const float* __restrict__ wq,
                                            const float* __restrict__ wk,
                                            const float* __restrict__ wv,
                                            const float* __restrict__ wo,
                                            unsigned short* __restrict__ out) {
  int i = blockIdx.x * 256 + threadIdx.x;
  int seg = i >> 18;
  int off = (i & 0x3ffff) << 2;
  const float* src = (seg == 0) ? wq : (seg == 1) ? wk : (seg == 2) ? wv : wo;
  f32x4 v = *(const f32x4*)(src + off);
  ushort4v o;
#pragma unroll
  for (int j = 0; j < 4; ++j) o[j] = f2b(v[j]);
  *(ushort4v*)(out + ((size_t)seg << 20) + off) = o;
}

// ---------------------------------------------------------------------------
// Input convert: query/key/value fp32 -> bf16 (grid-stride, memory-bound)
// ---------------------------------------------------------------------------
__global__ __launch_bounds__(256) void cvt_qkv(const float* __restrict__ q,
                                               const float* __restrict__ k,
                                               const float* __restrict__ v,
                                               unsigned short* __restrict__ qb,
                                               unsigned short* __restrict__ kb,
                                               unsigned short* __restrict__ vb) {
  const int Q4 = 131072, K4 = 8388608;         // float4 counts
  const int total = Q4 + 2 * K4;
  for (int i = blockIdx.x * 256 + threadIdx.x; i < total; i += gridDim.x * 256) {
    const float* src; unsigned short* dst; int off;
    if (i < Q4)            { src = q; dst = qb; off = i; }
    else if (i < Q4 + K4)  { src = k; dst = kb; off = i - Q4; }
    else                   { src = v; dst = vb; off = i - Q4 - K4; }
    f32x4 x = *(const f32x4*)(src + (size_t)off * 4);
    ushort4v o;
#pragma unroll
    for (int j = 0; j < 4; ++j) o[j] = f2b(x[j]);
    *(ushort4v*)(dst + (size_t)off * 4) = o;
  }
}

// ---------------------------------------------------------------------------
// GEMM: C[M][1024] = A[M][1024](bf16) @ W[1024][1024]^T(bf16)
//  m97 structure: 128x128 tile, BK=32, 4 waves (2x2), global_load_lds(16B)
//  both operands, double-buffered linear LDS, 1 barrier/K-step,
//  8 ds_read_b128 + 16 MFMA per K-step, XCD-chunked n-fast grid swizzle.
//  grid.x = (M/128)*8, must be %8==0 (true: 32 and 2048).
// ---------------------------------------------------------------------------
template <bool OUT_F32B>
__global__ __launch_bounds__(256) void gemm_bf16(const unsigned short* __restrict__ A,
                                                 const unsigned short* __restrict__ W,
                                                 void* __restrict__ Cp,
                                                 const float* __restrict__ bias) {
  __shared__ __align__(16) char smem[34816];   // 4x8KB staging; epilogue reuses all
  const int tid = threadIdx.x, lane = tid & 63, wv = tid >> 6;
  const int g = lane >> 4, c15 = lane & 15;
  const int wm = wv >> 1, wn = wv & 1;

  const int nwg = gridDim.x;
  const int swz = (blockIdx.x & 7) * (nwg >> 3) + (blockIdx.x >> 3);
  const long m0 = (long)(swz >> 3) * 128;
  const int  n0 = (swz & 7) * 128;

  // staging: 4 lanes/row, 8 bf16 (16B) per lane; wave w covers 16 rows/issue
  const int srow = lane >> 2, scol = (lane & 3) * 8;
  const unsigned short* a_src = A + (m0 + srow) * 1024 + scol;
  const unsigned short* b_src = W + (long)(n0 + srow) * 1024 + scol;

  f32x4 acc[4][4] = {};

  auto stage = [&](int buf, int kt) {
    unsigned short* al = (unsigned short*)(smem + buf * 8192);
    unsigned short* bl = (unsigned short*)(smem + 16384 + buf * 8192);
#pragma unroll
    for (int q = 0; q < 2; ++q) {
      const int rbase = q * 64 + wv * 16;                 // wave-uniform
      gl2lds16(a_src + (long)rbase * 1024 + kt * 32, al + rbase * 32);
      gl2lds16(b_src + (long)rbase * 1024 + kt * 32, bl + rbase * 32);
    }
  };

  stage(0, 0);
  __syncthreads();

  int cur = 0;
  for (int kt = 0; kt < 32; ++kt) {
    if (kt + 1 < 32) stage(cur ^ 1, kt + 1);
    const unsigned short* al = (const unsigned short*)(smem + cur * 8192);
    const unsigned short* bl = (const unsigned short*)(smem + 16384 + cur * 8192);
    short8 af[4];
#pragma unroll
    for (int m = 0; m < 4; ++m)
      af[m] = *(const short8*)&al[(wm * 64 + m * 16 + c15) * 32 + g * 8];
#pragma unroll
    for (int n = 0; n < 4; ++n) {
      short8 b8 = *(const short8*)&bl[(wn * 64 + n * 16 + c15) * 32 + g * 8];
#pragma unroll
      for (int m = 0; m < 4; ++m)
        acc[m][n] = __builtin_amdgcn_mfma_f32_16x16x32_bf16(af[m], b8, acc[m][n], 0, 0, 0);
    }
    __syncthreads();          // staged next buf visible; cur reads complete
    cur ^= 1;
  }

  if constexpr (OUT_F32B) {
    float* Cf = (float*)Cp;
#pragma unroll
    for (int m = 0; m < 4; ++m)
#pragma unroll
      for (int n = 0; n < 4; ++n)
#pragma unroll
        for (int r = 0; r < 4; ++r) {
          long row = m0 + wm * 64 + m * 16 + g * 4 + r;
          int  col = n0 + wn * 64 + n * 16 + c15;
          Cf[row * 1024 + col] = acc[m][n][r] + bias[col];
        }
  } else {
    unsigned short* c_lds = (unsigned short*)smem;   // [128][132] = 33792 B
#pragma unroll
    for (int m = 0; m < 4; ++m)
#pragma unroll
      for (int n = 0; n < 4; ++n)
#pragma unroll
        for (int r = 0; r < 4; ++r)
          c_lds[(wm * 64 + m * 16 + g * 4 + r) * 132 + wn * 64 + n * 16 + c15] =
              f2b(acc[m][n][r]);
    __syncthreads();
    unsigned short* Cb = (unsigned short*)Cp;
    const int row = tid >> 1, half = tid & 1;
    unsigned short*       dst = Cb + (m0 + row) * 1024 + n0 + half * 64;
    const unsigned short* sl  = &c_lds[row * 132 + half * 64];
#pragma unroll
    for (int i = 0; i < 8; ++i)
      *(ushort8*)(dst + i * 8) = *(const ushort8*)(sl + i * 8);
  }
}

// ---------------------------------------------------------------------------
// Attention pass 1 (L-split x4): partial rowsums over 1024 keys per block.
// ---------------------------------------------------------------------------
__global__ __launch_bounds__(512) void attn_pass1(const unsigned short* __restrict__ q_b,
                                                  const unsigned short* __restrict__ k_b,
                                                  float* __restrict__ rs_part) {
  __shared__ unsigned short q_lds[64][72];
  __shared__ unsigned short k_lds[128][72];
  __shared__ float rs_lds[8][64];
  const int bh = blockIdx.x >> 2, ch = blockIdx.x & 3;
  const int b = bh >> 4, h = bh & 15;
  const int tid = threadIdx.x;
  const int w = tid >> 6, lane = tid & 63;
  const int g = lane >> 4, c15 = lane & 15;

  {
    int slot = tid >> 3, cc = (tid & 7) * 8;
    *(ushort8*)&q_lds[slot][cc] =
        *(const ushort8*)(q_b + (long)(b * 64 + slot) * 1024 + h * 64 + cc);
  }

  float rs[4][4] = {};
  const long kbase = (long)b * L_ * D_ + h * 64;
  const int  sl = tid >> 2, sc = (tid & 3) * 16;

  for (int it = ch * 8; it < ch * 8 + 8; ++it) {
    const int l0 = it * 128;
    ushort8 k0 = *(const ushort8*)(k_b + kbase + (long)(l0 + sl) * 1024 + sc);
    ushort8 k1 = *(const ushort8*)(k_b + kbase + (long)(l0 + sl) * 1024 + sc + 8);
    __syncthreads();
    *(ushort8*)&k_lds[sl][sc]     = k0;
    *(ushort8*)&k_lds[sl][sc + 8] = k1;
    __syncthreads();

    f32x4 s[4] = {};
#pragma unroll
    for (int ks = 0; ks < 2; ++ks) {
      short8 bf = *(const short8*)&k_lds[w * 16 + c15][ks * 32 + g * 8];
#pragma unroll
      for (int m = 0; m < 4; ++m) {
        short8 af = *(const short8*)&q_lds[m * 16 + c15][ks * 32 + g * 8];
        s[m] = __builtin_amdgcn_mfma_f32_16x16x32_bf16(af, bf, s[m], 0, 0, 0);
      }
    }
    float mx = -1e30f;
#pragma unroll
    for (int m = 0; m < 4; ++m)
#pragma unroll
      for (int r = 0; r < 4; ++r) mx = fmaxf(mx, s[m][r]);
    mx = fmaxf(mx, __shfl_xor(mx, 16));
    mx = fmaxf(mx, __shfl_xor(mx, 32));
    float sum = 0.f, p[4][4];
#pragma unroll
    for (int m = 0; m < 4; ++m)
#pragma unroll
      for (int r = 0; r < 4; ++r) { p[m][r] = __expf((s[m][r] - mx) * SCALE_); sum += p[m][r]; }
    sum += __shfl_xor(sum, 16);
    sum += __shfl_xor(sum, 32);
    float rinv = 1.0f / sum;
#pragma unroll
    for (int m = 0; m < 4; ++m)
#pragma unroll
      for (int r = 0; r < 4; ++r) rs[m][r] += p[m][r] * rinv;
  }
#pragma unroll
  for (int m = 0; m < 4; ++m)
#pragma unroll
    for (int r = 0; r < 4; ++r) {
      float v = rs[m][r];
      v += __shfl_xor(v, 1); v += __shfl_xor(v, 2);
      v += __shfl_xor(v, 4); v += __shfl_xor(v, 8);
      if (c15 == 0) rs_lds[w][m * 16 + g * 4 + r] = v;
    }
  __syncthreads();
  if (tid < 64) {
    float t = 0.f;
#pragma unroll
    for (int w2 = 0; w2 < 8; ++w2) t += rs_lds[w2][tid];
    rs_part[(bh * 4 + ch) * 64 + tid] = t;
  }
}

// ---------------------------------------------------------------------------
// Attention pass 2 (L-split x4): recompute softmax, scale, write attn fp32,
// PV partial -> op_part fp32.
// ---------------------------------------------------------------------------
__global__ __launch_bounds__(512) void attn_pass2(const unsigned short* __restrict__ q_b,
                                                  const unsigned short* __restrict__ k_b,
                                                  const unsigned short* __restrict__ v_b,
                                                  const float* __restrict__ rs_part,
                                                  float* __restrict__ attn,
                                                  float* __restrict__ op_part) {
  __shared__ unsigned short q_lds[64][72];
  __shared__ unsigned short k_lds[128][72];
  __shared__ unsigned short vt_lds[64][136];
  __shared__ unsigned short pt_lds[64][136];
  const int bh = blockIdx.x >> 2, ch = blockIdx.x & 3;
  const int b = bh >> 4, h = bh & 15;
  const int tid = threadIdx.x;
  const int w = tid >> 6, lane = tid & 63;
  const int g = lane >> 4, c15 = lane & 15;

  {
    int slot = tid >> 3, cc = (tid & 7) * 8;
    *(ushort8*)&q_lds[slot][cc] =
        *(const ushort8*)(q_b + (long)(b * 64 + slot) * 1024 + h * 64 + cc);
  }

  float inv_r[4][4];
#pragma unroll
  for (int m = 0; m < 4; ++m)
#pragma unroll
    for (int r = 0; r < 4; ++r) {
      int slot = m * 16 + g * 4 + r;
      float s = 0.f;
#pragma unroll
      for (int c = 0; c < 4; ++c) s += rs_part[(bh * 4 + c) * 64 + slot];
      inv_r[m][r] = 1.0f / (s + 1e-8f);
    }

  f32x4 oacc[2] = {};
  const int m_pv = w >> 1, n_pv0 = (w & 1) * 2;
  float* attn_base = attn + (long)bh * KS_ * L_;
  const long base_bld = (long)b * L_ * D_ + h * 64;
  const int  sl = tid >> 2, sc = (tid & 3) * 16;

  for (int it = ch * 8; it < ch * 8 + 8; ++it) {
    const int l0 = it * 128;
    ushort8 k0 = *(const ushort8*)(k_b + base_bld + (long)(l0 + sl) * 1024 + sc);
    ushort8 k1 = *(const ushort8*)(k_b + base_bld + (long)(l0 + sl) * 1024 + sc + 8);
    ushort8 v0 = *(const ushort8*)(v_b + base_bld + (long)(l0 + sl) * 1024 + sc);
    ushort8 v1 = *(const ushort8*)(v_b + base_bld + (long)(l0 + sl) * 1024 + sc + 8);
    __syncthreads();
    *(ushort8*)&k_lds[sl][sc]     = k0;
    *(ushort8*)&k_lds[sl][sc + 8] = k1;
#pragma unroll
    for (int j = 0; j < 8; ++j) {
      vt_lds[sc + j][sl]     = v0[j];
      vt_lds[sc + 8 + j][sl] = v1[j];
    }
    __syncthreads();

    f32x4 s[4] = {};
#pragma unroll
    for (int ks = 0; ks < 2; ++ks) {
      short8 bf = *(const short8*)&k_lds[w * 16 + c15][ks * 32 + g * 8];
#pragma unroll
      for (int m = 0; m < 4; ++m) {
        short8 af = *(const short8*)&q_lds[m * 16 + c15][ks * 32 + g * 8];
        s[m] = __builtin_amdgcn_mfma_f32_16x16x32_bf16(af, bf, s[m], 0, 0, 0);
      }
    }
    float mx = -1e30f;
#pragma unroll
    for (int m = 0; m < 4; ++m)
#pragma unroll
      for (int r = 0; r < 4; ++r) mx = fmaxf(mx, s[m][r]);
    mx = fmaxf(mx, __shfl_xor(mx, 16));
    mx = fmaxf(mx, __shfl_xor(mx, 32));
    float sum = 0.f, p[4][4];
#pragma unroll
    for (int m = 0; m < 4; ++m)
#pragma unroll
      for (int r = 0; r < 4; ++r) { p[m][r] = __expf((s[m][r] - mx) * SCALE_); sum += p[m][r]; }
    sum += __shfl_xor(sum, 16);
    sum += __shfl_xor(sum, 32);
    float rinv = 1.0f / sum;

    const int lloc = w * 16 + c15;
#pragma unroll
    for (int m = 0; m < 4; ++m)
#pragma unroll
      for (int r = 0; r < 4; ++r) {
        float ps = p[m][r] * rinv * inv_r[m][r];
        attn_base[(long)(m * 16 + g * 4 + r) * L_ + l0 + lloc] = ps;
        pt_lds[m * 16 + g * 4 + r][lloc] = f2b(ps);
      }
    __syncthreads();

#pragma unroll
    for (int ks = 0; ks < 4; ++ks) {
      short8 pa = *(const short8*)&pt_lds[m_pv * 16 + c15][ks * 32 + g * 8];
#pragma unroll
      for (int n2 = 0; n2 < 2; ++n2) {
        short8 vb = *(const short8*)&vt_lds[(n_pv0 + n2) * 16 + c15][ks * 32 + g * 8];
        oacc[n2] = __builtin_amdgcn_mfma_f32_16x16x32_bf16(pa, vb, oacc[n2], 0, 0, 0);
      }
    }
  }

#pragma unroll
  for (int n2 = 0; n2 < 2; ++n2)
#pragma unroll
    for (int r = 0; r < 4; ++r) {
      int slot = m_pv * 16 + g * 4 + r;
      int c    = (n_pv0 + n2) * 16 + c15;
      op_part[((long)(bh * 4 + ch) * 64 + slot) * 64 + c] = oacc[n2][r];
    }
}

// ---------------------------------------------------------------------------
// Reduce PV chunk-partials -> oh bf16 [512][1024]
// ---------------------------------------------------------------------------
__global__ __launch_bounds__(256) void oh_red(const float* __restrict__ op_part,
                                              unsigned short* __restrict__ oh) {
  int i = blockIdx.x * 256 + threadIdx.x;   // 524288 total
  int c = i & 63, slot = (i >> 6) & 63, bh = i >> 12;
  float s = 0.f;
#pragma unroll
  for (int ch = 0; ch < 4; ++ch)
    s += op_part[((long)(bh * 4 + ch) * 64 + slot) * 64 + c];
  int b = bh >> 4, h = bh & 15;
  oh[(long)(b * 64 + slot) * 1024 + h * 64 + c] = f2b(s);
}

// ---------------------------------------------------------------------------
extern "C" void kernel_launch(void* const* d_in, const int* in_sizes, int n_in,
                              void* d_out, int out_size, void* d_ws, size_t ws_size,
                              hipStream_t stream) {
  (void)in_sizes; (void)n_in; (void)out_size; (void)ws_size;
  const float* query = (const float*)d_in[0];
  const float* key   = (const float*)d_in[1];
  const float* value = (const float*)d_in[2];
  const float* Wq    = (const float*)d_in[3];
  const float* Wk    = (const float*)d_in[4];
  const float* Wv    = (const float*)d_in[5];
  const float* Wo    = (const float*)d_in[6];
  const float* bo    = (const float*)d_in[7];

  char* ws = (char*)d_ws;
  // ws layout (~147 MB)
  unsigned short* w_all   = (unsigned short*)ws;                        // 8 MB
  unsigned short* wq_b    = w_all;
  unsigned short* wk_b    = w_all + (1u << 20);
  unsigned short* wv_b    = w_all + (2u << 20);
  unsigned short* wo_b    = w_all + (3u << 20);
  unsigned short* qin_b   = (unsigned short*)(ws + ((size_t)8  << 20)); // 1 MB
  unsigned short* q_b     = (unsigned short*)(ws + ((size_t)9  << 20)); // 1 MB
  unsigned short* oh_b    = (unsigned short*)(ws + ((size_t)10 << 20)); // 1 MB
  float*          rs_part = (float*)         (ws + ((size_t)11 << 20)); // 128 KB
  float*          op_part = (float*)         (ws + ((size_t)12 << 20)); // 8 MB
  unsigned short* k_b     = (unsigned short*)(ws + ((size_t)20 << 20)); // 64 MB
  unsigned short* v_b     = (unsigned short*)(ws + ((size_t)84 << 20)); // 64 MB

  float* out  = (float*)d_out;
  float* attn = out + (size_t)B_ * KS_ * D_;

  // converted K/V inputs live in the (not-yet-written) attn output region:
  // 64 MiB + 64 MiB = exactly the 128 MiB attn buffer. They are fully
  // consumed by the K/V projections, which run before attn_pass2 writes attn.
  unsigned short* kin_b = (unsigned short*)attn;
  unsigned short* vin_b = (unsigned short*)attn + ((size_t)32 << 20);

  wcvt<<<4096, 256, 0, stream>>>(Wq, Wk, Wv, Wo, w_all);
  cvt_qkv<<<2048, 256, 0, stream>>>(query, key, value, qin_b, kin_b, vin_b);

  gemm_bf16<false><<<32,   256, 0, stream>>>(qin_b, wq_b, q_b, nullptr);
  gemm_bf16<false><<<2048, 256, 0, stream>>>(kin_b, wk_b, k_b, nullptr);
  gemm_bf16<false><<<2048, 256, 0, stream>>>(vin_b, wv_b, v_b, nullptr);

  attn_pass1<<<512, 512, 0, stream>>>(q_b, k_b, rs_part);
  attn_pass2<<<512, 512, 0, stream>>>(q_b, k_b, v_b, rs_part, attn, op_part);
  oh_red<<<2048, 256, 0, stream>>>(op_part, oh_b);

  gemm_bf16<true><<<32, 256, 0, stream>>>(oh_b, wo_b, out, bo);
}

// Round 4
// 413.829 us; speedup vs baseline: 1.2208x; 1.0171x over previous
//
#include <hip/hip_runtime.h>
#include <hip/hip_bf16.h>

#define B_   8
#define KS_  64
#define L_   4096
#define D_   1024
#define H_   16
#define HD_  64
#define SCALE_ 0.125f

typedef __attribute__((ext_vector_type(8))) short short8;
typedef __attribute__((ext_vector_type(8))) unsigned short ushort8;
typedef __attribute__((ext_vector_type(4))) unsigned short ushort4v;
typedef __attribute__((ext_vector_type(4))) float f32x4;

__device__ __forceinline__ unsigned short f2b(float f) {
  union { float f; unsigned u; } v; v.f = f;
  unsigned r = v.u + 0x7fffu + ((v.u >> 16) & 1u);
  return (unsigned short)(r >> 16);
}

// HW packed fp32->bf16 (RTNE), 2 elems / 1 VALU op. No builtin on gfx950 (m240).
__device__ __forceinline__ unsigned cvtpk(float a, float b) {
  unsigned r;
  asm("v_cvt_pk_bf16_f32 %0, %1, %2" : "=v"(r) : "v"(a), "v"(b));
  return r;
}

typedef const __attribute__((address_space(1))) void gas_void;
typedef __attribute__((address_space(3))) void las_void;
__device__ __forceinline__ void gl2lds16(const void* g, void* l) {
  __builtin_amdgcn_global_load_lds((gas_void*)g, (las_void*)l, 16, 0, 0);
}

// ---------------------------------------------------------------------------
// Weight convert: 4 x [1024x1024] fp32 -> bf16 contiguous in ws
// ---------------------------------------------------------------------------
__global__ __launch_bounds__(256) void wcvt(const float* __restrict__ wq,
                                            const float* __restrict__ wk,
                                            const float* __restrict__ wv,
                                            const float* __restrict__ wo,
                                            unsigned short* __restrict__ out) {
  int i = blockIdx.x * 256 + threadIdx.x;
  int seg = i >> 18;
  int off = (i & 0x3ffff) << 2;
  const float* src = (seg == 0) ? wq : (seg == 1) ? wk : (seg == 2) ? wv : wo;
  f32x4 v = *(const f32x4*)(src + off);
  ushort4v o;
#pragma unroll
  for (int j = 0; j < 4; ++j) o[j] = f2b(v[j]);
  *(ushort4v*)(out + ((size_t)seg << 20) + off) = o;
}

// ---------------------------------------------------------------------------
// GEMM: C[M][1024] = A[M][1024](fp32!) @ W[1024][1024]^T(bf16)
//  128x128 tile, BK=32, 4 waves (2x2), global_load_lds(16B) both operands,
//  static double-buffered LDS (K-loop unrolled x2), 1 barrier/K-step,
//  XCD-chunked n-fast grid swizzle.
//  A staged fp32 [128][32] (16KB) with XOR swizzle x^=((x>>7)&7)<<4 applied on
//  BOTH sides (pre-swizzled global source + swizzled ds_read, rule#21) ->
//  b128 reads at the 8-pass bank floor. Converted to bf16 at frag read via
//  v_cvt_pk_bf16_f32 (4 ops per frag). B bf16 [128][32] linear (already at
//  floor). grid.x = (M/128)*8, %8==0.
// ---------------------------------------------------------------------------
template <bool OUT_F32B>
__global__ __launch_bounds__(256) void gemm_af32(const float* __restrict__ A,
                                                 const unsigned short* __restrict__ W,
                                                 void* __restrict__ Cp,
                                                 const float* __restrict__ bias) {
  __shared__ __align__(16) char smem[49152];   // A:2x16KB, B:2x8KB; epi reuses
  const int tid = threadIdx.x, lane = tid & 63, wv = tid >> 6;
  const int g = lane >> 4, c15 = lane & 15;
  const int wm = wv >> 1, wn = wv & 1;

  const int nwg = gridDim.x;
  const int swz = (blockIdx.x & 7) * (nwg >> 3) + (blockIdx.x >> 3);
  const long m0 = (long)(swz >> 3) * 128;
  const int  n0 = (swz & 7) * 128;

  // A staging: 8 lanes/row (16B=4 f32 each); fetch column pre-swizzled so the
  // linear gl2lds write lands data at swz(logical) physically.
  const int a_rl = lane >> 3;                       // row-in-8 (= r&7 per load)
  const int a_cs = ((lane & 7) ^ a_rl) * 4;         // swizzled f32 col chunk
  const float* a_lane = A + (m0 + a_rl) * 1024 + a_cs;
  // B staging: 4 lanes/row, 8 bf16 (16B) per lane
  const unsigned short* b_lane = W + (long)(n0 + (lane >> 2)) * 1024 + (lane & 3) * 8;

  f32x4 acc[4][4] = {};

  auto stage = [&](int buf, int kt) {
    char* abase = smem + buf * 16384;
    char* bbase = smem + 32768 + buf * 8192;
#pragma unroll
    for (int q = 0; q < 4; ++q) {                   // A: 4 x 8 rows
      const int r0 = wv * 32 + q * 8;
      gl2lds16(a_lane + (long)r0 * 1024 + kt * 32, abase + r0 * 128);
    }
#pragma unroll
    for (int q = 0; q < 2; ++q) {                   // B: 2 x 16 rows
      const int r0 = (wv * 2 + q) * 16;
      gl2lds16(b_lane + (long)r0 * 1024 + kt * 32, bbase + r0 * 64);
    }
  };

  auto compute = [&](int buf) {
    const char* ab = smem + buf * 16384;
    const unsigned short* bl = (const unsigned short*)(smem + 32768 + buf * 8192);
    short8 af[4];
    const int ro = (c15 & 7) << 4;                  // R&7 == c15&7
#pragma unroll
    for (int m = 0; m < 4; ++m) {
      const int R = wm * 64 + m * 16 + c15;
      f32x4 lo = *(const f32x4*)(ab + R * 128 + ((g * 32) ^ ro));
      f32x4 hi = *(const f32x4*)(ab + R * 128 + ((g * 32 + 16) ^ ro));
      union { unsigned u[4]; short8 s; } t;
      t.u[0] = cvtpk(lo[0], lo[1]); t.u[1] = cvtpk(lo[2], lo[3]);
      t.u[2] = cvtpk(hi[0], hi[1]); t.u[3] = cvtpk(hi[2], hi[3]);
      af[m] = t.s;
    }
#pragma unroll
    for (int n = 0; n < 4; ++n) {
      short8 b8 = *(const short8*)&bl[(wn * 64 + n * 16 + c15) * 32 + g * 8];
#pragma unroll
      for (int m = 0; m < 4; ++m)
        acc[m][n] = __builtin_amdgcn_mfma_f32_16x16x32_bf16(af[m], b8, acc[m][n], 0, 0, 0);
    }
  };

  stage(0, 0);
  __syncthreads();

#pragma unroll 1
  for (int kt = 0; kt < 32; kt += 2) {              // static dbuf: 0,1 literal
    stage(1, kt + 1);
    compute(0);
    __syncthreads();
    if (kt + 2 < 32) stage(0, kt + 2);
    compute(1);
    __syncthreads();
  }

  if constexpr (OUT_F32B) {
    float* Cf = (float*)Cp;
#pragma unroll
    for (int m = 0; m < 4; ++m)
#pragma unroll
      for (int n = 0; n < 4; ++n)
#pragma unroll
        for (int r = 0; r < 4; ++r) {
          long row = m0 + wm * 64 + m * 16 + g * 4 + r;
          int  col = n0 + wn * 64 + n * 16 + c15;
          Cf[row * 1024 + col] = acc[m][n][r] + bias[col];
        }
  } else {
    unsigned short* c_lds = (unsigned short*)smem;  // [128][132] = 33792 B
#pragma unroll
    for (int m = 0; m < 4; ++m)
#pragma unroll
      for (int n = 0; n < 4; ++n)
#pragma unroll
        for (int r = 0; r < 4; ++r)
          c_lds[(wm * 64 + m * 16 + g * 4 + r) * 132 + wn * 64 + n * 16 + c15] =
              f2b(acc[m][n][r]);
    __syncthreads();
    unsigned short* Cb = (unsigned short*)Cp;
    const int row = tid >> 1, half = tid & 1;
    unsigned short*       dst = Cb + (m0 + row) * 1024 + n0 + half * 64;
    const unsigned short* sl  = &c_lds[row * 132 + half * 64];
#pragma unroll
    for (int i = 0; i < 8; ++i)
      *(ushort8*)(dst + i * 8) = *(const ushort8*)(sl + i * 8);
  }
}

// ---------------------------------------------------------------------------
// Attention pass 1 (L-split x4): partial rowsums over 1024 keys per block.
// ---------------------------------------------------------------------------
__global__ __launch_bounds__(512) void attn_pass1(const unsigned short* __restrict__ q_b,
                                                  const unsigned short* __restrict__ k_b,
                                                  float* __restrict__ rs_part) {
  __shared__ unsigned short q_lds[64][72];
  __shared__ unsigned short k_lds[128][72];
  __shared__ float rs_lds[8][64];
  const int bh = blockIdx.x >> 2, ch = blockIdx.x & 3;
  const int b = bh >> 4, h = bh & 15;
  const int tid = threadIdx.x;
  const int w = tid >> 6, lane = tid & 63;
  const int g = lane >> 4, c15 = lane & 15;

  {
    int slot = tid >> 3, cc = (tid & 7) * 8;
    *(ushort8*)&q_lds[slot][cc] =
        *(const ushort8*)(q_b + (long)(b * 64 + slot) * 1024 + h * 64 + cc);
  }

  float rs[4][4] = {};
  const long kbase = (long)b * L_ * D_ + h * 64;
  const int  sl = tid >> 2, sc = (tid & 3) * 16;

  for (int it = ch * 8; it < ch * 8 + 8; ++it) {
    const int l0 = it * 128;
    ushort8 k0 = *(const ushort8*)(k_b + kbase + (long)(l0 + sl) * 1024 + sc);
    ushort8 k1 = *(const ushort8*)(k_b + kbase + (long)(l0 + sl) * 1024 + sc + 8);
    __syncthreads();
    *(ushort8*)&k_lds[sl][sc]     = k0;
    *(ushort8*)&k_lds[sl][sc + 8] = k1;
    __syncthreads();

    f32x4 s[4] = {};
#pragma unroll
    for (int ks = 0; ks < 2; ++ks) {
      short8 bf = *(const short8*)&k_lds[w * 16 + c15][ks * 32 + g * 8];
#pragma unroll
      for (int m = 0; m < 4; ++m) {
        short8 af = *(const short8*)&q_lds[m * 16 + c15][ks * 32 + g * 8];
        s[m] = __builtin_amdgcn_mfma_f32_16x16x32_bf16(af, bf, s[m], 0, 0, 0);
      }
    }
    float mx = -1e30f;
#pragma unroll
    for (int m = 0; m < 4; ++m)
#pragma unroll
      for (int r = 0; r < 4; ++r) mx = fmaxf(mx, s[m][r]);
    mx = fmaxf(mx, __shfl_xor(mx, 16));
    mx = fmaxf(mx, __shfl_xor(mx, 32));
    float sum = 0.f, p[4][4];
#pragma unroll
    for (int m = 0; m < 4; ++m)
#pragma unroll
      for (int r = 0; r < 4; ++r) { p[m][r] = __expf((s[m][r] - mx) * SCALE_); sum += p[m][r]; }
    sum += __shfl_xor(sum, 16);
    sum += __shfl_xor(sum, 32);
    float rinv = 1.0f / sum;
#pragma unroll
    for (int m = 0; m < 4; ++m)
#pragma unroll
      for (int r = 0; r < 4; ++r) rs[m][r] += p[m][r] * rinv;
  }
#pragma unroll
  for (int m = 0; m < 4; ++m)
#pragma unroll
    for (int r = 0; r < 4; ++r) {
      float v = rs[m][r];
      v += __shfl_xor(v, 1); v += __shfl_xor(v, 2);
      v += __shfl_xor(v, 4); v += __shfl_xor(v, 8);
      if (c15 == 0) rs_lds[w][m * 16 + g * 4 + r] = v;
    }
  __syncthreads();
  if (tid < 64) {
    float t = 0.f;
#pragma unroll
    for (int w2 = 0; w2 < 8; ++w2) t += rs_lds[w2][tid];
    rs_part[(bh * 4 + ch) * 64 + tid] = t;
  }
}

// ---------------------------------------------------------------------------
// Attention pass 2 (L-split x4): recompute softmax, scale, write attn fp32,
// PV partial -> op_part fp32.
// ---------------------------------------------------------------------------
__global__ __launch_bounds__(512) void attn_pass2(const unsigned short* __restrict__ q_b,
                                                  const unsigned short* __restrict__ k_b,
                                                  const unsigned short* __restrict__ v_b,
                                                  const float* __restrict__ rs_part,
                                                  float* __restrict__ attn,
                                                  float* __restrict__ op_part) {
  __shared__ unsigned short q_lds[64][72];
  __shared__ unsigned short k_lds[128][72];
  __shared__ unsigned short vt_lds[64][136];
  __shared__ unsigned short pt_lds[64][136];
  const int bh = blockIdx.x >> 2, ch = blockIdx.x & 3;
  const int b = bh >> 4, h = bh & 15;
  const int tid = threadIdx.x;
  const int w = tid >> 6, lane = tid & 63;
  const int g = lane >> 4, c15 = lane & 15;

  {
    int slot = tid >> 3, cc = (tid & 7) * 8;
    *(ushort8*)&q_lds[slot][cc] =
        *(const ushort8*)(q_b + (long)(b * 64 + slot) * 1024 + h * 64 + cc);
  }

  float inv_r[4][4];
#pragma unroll
  for (int m = 0; m < 4; ++m)
#pragma unroll
    for (int r = 0; r < 4; ++r) {
      int slot = m * 16 + g * 4 + r;
      float s = 0.f;
#pragma unroll
      for (int c = 0; c < 4; ++c) s += rs_part[(bh * 4 + c) * 64 + slot];
      inv_r[m][r] = 1.0f / (s + 1e-8f);
    }

  f32x4 oacc[2] = {};
  const int m_pv = w >> 1, n_pv0 = (w & 1) * 2;
  float* attn_base = attn + (long)bh * KS_ * L_;
  const long base_bld = (long)b * L_ * D_ + h * 64;
  const int  sl = tid >> 2, sc = (tid & 3) * 16;

  for (int it = ch * 8; it < ch * 8 + 8; ++it) {
    const int l0 = it * 128;
    ushort8 k0 = *(const ushort8*)(k_b + base_bld + (long)(l0 + sl) * 1024 + sc);
    ushort8 k1 = *(const ushort8*)(k_b + base_bld + (long)(l0 + sl) * 1024 + sc + 8);
    ushort8 v0 = *(const ushort8*)(v_b + base_bld + (long)(l0 + sl) * 1024 + sc);
    ushort8 v1 = *(const ushort8*)(v_b + base_bld + (long)(l0 + sl) * 1024 + sc + 8);
    __syncthreads();
    *(ushort8*)&k_lds[sl][sc]     = k0;
    *(ushort8*)&k_lds[sl][sc + 8] = k1;
#pragma unroll
    for (int j = 0; j < 8; ++j) {
      vt_lds[sc + j][sl]     = v0[j];
      vt_lds[sc + 8 + j][sl] = v1[j];
    }
    __syncthreads();

    f32x4 s[4] = {};
#pragma unroll
    for (int ks = 0; ks < 2; ++ks) {
      short8 bf = *(const short8*)&k_lds[w * 16 + c15][ks * 32 + g * 8];
#pragma unroll
      for (int m = 0; m < 4; ++m) {
        short8 af = *(const short8*)&q_lds[m * 16 + c15][ks * 32 + g * 8];
        s[m] = __builtin_amdgcn_mfma_f32_16x16x32_bf16(af, bf, s[m], 0, 0, 0);
      }
    }
    float mx = -1e30f;
#pragma unroll
    for (int m = 0; m < 4; ++m)
#pragma unroll
      for (int r = 0; r < 4; ++r) mx = fmaxf(mx, s[m][r]);
    mx = fmaxf(mx, __shfl_xor(mx, 16));
    mx = fmaxf(mx, __shfl_xor(mx, 32));
    float sum = 0.f, p[4][4];
#pragma unroll
    for (int m = 0; m < 4; ++m)
#pragma unroll
      for (int r = 0; r < 4; ++r) { p[m][r] = __expf((s[m][r] - mx) * SCALE_); sum += p[m][r]; }
    sum += __shfl_xor(sum, 16);
    sum += __shfl_xor(sum, 32);
    float rinv = 1.0f / sum;

    const int lloc = w * 16 + c15;
#pragma unroll
    for (int m = 0; m < 4; ++m)
#pragma unroll
      for (int r = 0; r < 4; ++r) {
        float ps = p[m][r] * rinv * inv_r[m][r];
        attn_base[(long)(m * 16 + g * 4 + r) * L_ + l0 + lloc] = ps;
        pt_lds[m * 16 + g * 4 + r][lloc] = f2b(ps);
      }
    __syncthreads();

#pragma unroll
    for (int ks = 0; ks < 4; ++ks) {
      short8 pa = *(const short8*)&pt_lds[m_pv * 16 + c15][ks * 32 + g * 8];
#pragma unroll
      for (int n2 = 0; n2 < 2; ++n2) {
        short8 vb = *(const short8*)&vt_lds[(n_pv0 + n2) * 16 + c15][ks * 32 + g * 8];
        oacc[n2] = __builtin_amdgcn_mfma_f32_16x16x32_bf16(pa, vb, oacc[n2], 0, 0, 0);
      }
    }
  }

#pragma unroll
  for (int n2 = 0; n2 < 2; ++n2)
#pragma unroll
    for (int r = 0; r < 4; ++r) {
      int slot = m_pv * 16 + g * 4 + r;
      int c    = (n_pv0 + n2) * 16 + c15;
      op_part[((long)(bh * 4 + ch) * 64 + slot) * 64 + c] = oacc[n2][r];
    }
}

// ---------------------------------------------------------------------------
// Reduce PV chunk-partials -> oh fp32 [512][1024]
// ---------------------------------------------------------------------------
__global__ __launch_bounds__(256) void oh_red(const float* __restrict__ op_part,
                                              float* __restrict__ oh) {
  int i = blockIdx.x * 256 + threadIdx.x;   // 524288 total
  int c = i & 63, slot = (i >> 6) & 63, bh = i >> 12;
  float s = 0.f;
#pragma unroll
  for (int ch = 0; ch < 4; ++ch)
    s += op_part[((long)(bh * 4 + ch) * 64 + slot) * 64 + c];
  int b = bh >> 4, h = bh & 15;
  oh[(long)(b * 64 + slot) * 1024 + h * 64 + c] = s;
}

// ---------------------------------------------------------------------------
extern "C" void kernel_launch(void* const* d_in, const int* in_sizes, int n_in,
                              void* d_out, int out_size, void* d_ws, size_t ws_size,
                              hipStream_t stream) {
  (void)in_sizes; (void)n_in; (void)out_size; (void)ws_size;
  const float* query = (const float*)d_in[0];
  const float* key   = (const float*)d_in[1];
  const float* value = (const float*)d_in[2];
  const float* Wq    = (const float*)d_in[3];
  const float* Wk    = (const float*)d_in[4];
  const float* Wv    = (const float*)d_in[5];
  const float* Wo    = (const float*)d_in[6];
  const float* bo    = (const float*)d_in[7];

  char* ws = (char*)d_ws;
  // ws layout (~148 MB)
  unsigned short* w_all   = (unsigned short*)ws;                        // 8 MB
  unsigned short* wq_b    = w_all;
  unsigned short* wk_b    = w_all + (1u << 20);
  unsigned short* wv_b    = w_all + (2u << 20);
  unsigned short* wo_b    = w_all + (3u << 20);
  unsigned short* q_b     = (unsigned short*)(ws + ((size_t)8  << 20)); // 1 MB
  float*          oh_f32  = (float*)         (ws + ((size_t)9  << 20)); // 2 MB
  float*          rs_part = (float*)         (ws + ((size_t)11 << 20)); // 128 KB
  float*          op_part = (float*)         (ws + ((size_t)12 << 20)); // 8 MB
  unsigned short* k_b     = (unsigned short*)(ws + ((size_t)20 << 20)); // 64 MB
  unsigned short* v_b     = (unsigned short*)(ws + ((size_t)84 << 20)); // 64 MB

  float* out  = (float*)d_out;
  float* attn = out + (size_t)B_ * KS_ * D_;

  wcvt<<<4096, 256, 0, stream>>>(Wq, Wk, Wv, Wo, w_all);

  gemm_af32<false><<<32,   256, 0, stream>>>(query, wq_b, q_b, nullptr);
  gemm_af32<false><<<2048, 256, 0, stream>>>(key,   wk_b, k_b, nullptr);
  gemm_af32<false><<<2048, 256, 0, stream>>>(value, wv_b, v_b, nullptr);

  attn_pass1<<<512, 512, 0, stream>>>(q_b, k_b, rs_part);
  attn_pass2<<<512, 512, 0, stream>>>(q_b, k_b, v_b, rs_part, attn, op_part);
  oh_red<<<2048, 256, 0, stream>>>(op_part, oh_f32);

  gemm_af32<true><<<32, 256, 0, stream>>>(oh_f32, wo_b, out, bo);
}